// Round 4
// baseline (565.927 us; speedup 1.0000x reference)
//
#include <hip/hip_runtime.h>

#define BT_D   512
#define BT_D4  128   // float4 groups per row
#define NBLK   1024  // 4 blocks/CU
#define NTHR   512   // 8 waves/block -> 32 waves/CU

// native vector type: __builtin_nontemporal_load rejects HIP_vector_type
typedef float nf4 __attribute__((ext_vector_type(4)));

// Accumulate one (e,tau) nf4 pair into the 5 stat accumulators.
#define BT_ACC(ev, tv)                                                  \
    do {                                                                \
        se.x += (ev).x; se.y += (ev).y; se.z += (ev).z; se.w += (ev).w; \
        st.x += (tv).x; st.y += (tv).y; st.z += (tv).z; st.w += (tv).w; \
        se2.x = fmaf((ev).x, (ev).x, se2.x);                            \
        se2.y = fmaf((ev).y, (ev).y, se2.y);                            \
        se2.z = fmaf((ev).z, (ev).z, se2.z);                            \
        se2.w = fmaf((ev).w, (ev).w, se2.w);                            \
        st2.x = fmaf((tv).x, (tv).x, st2.x);                            \
        st2.y = fmaf((tv).y, (tv).y, st2.y);                            \
        st2.z = fmaf((tv).z, (tv).z, st2.z);                            \
        st2.w = fmaf((tv).w, (tv).w, st2.w);                            \
        set.x = fmaf((ev).x, (tv).x, set.x);                            \
        set.y = fmaf((ev).y, (tv).y, set.y);                            \
        set.z = fmaf((ev).z, (tv).z, set.z);                            \
        set.w = fmaf((ev).w, (tv).w, set.w);                            \
    } while (0)

#define BT_ADD4(dst, a) \
    do { (dst).x += (a).x; (dst).y += (a).y; (dst).z += (a).z; (dst).w += (a).w; } while (0)

#define BT_FIN(Se_, Se2_, St_, St2_, Set_)                               \
    do {                                                                 \
        const double Se = (Se_), Se2 = (Se2_), St = (St_), St2 = (St2_), \
                     Set = (Set_);                                       \
        const double me = Se / Bd, mt = St / Bd;                         \
        double ve = (Se2 - Bd * me * me) / (Bd - 1.0);                   \
        double vt = (St2 - Bd * mt * mt) / (Bd - 1.0);                   \
        ve = ve > 0.0 ? ve : 0.0;                                        \
        vt = vt > 0.0 ? vt : 0.0;                                        \
        const double sd_e = sqrt(ve) + 1e-9;                             \
        const double sd_t = sqrt(vt) + 1e-9;                             \
        const double c = (Set - Bd * me * mt) / (sd_e * sd_t * Bd);      \
        vsum += (1.0 - c) * (1.0 - c);                                   \
    } while (0)

// Fused kernel.
// Phase 1: R1's streaming partial (best measured: 108 µs) but with
//   NON-TEMPORAL loads — tests the "LLC thrash caps BW at ~2.5 TB/s" theory
//   (268 MB stream through a 256 MB LLC; FETCH_SIZE was exactly 50%).
// Phase 2: block fold + per-slot atomics (unchanged).
// Phase 3: last-block-done counter; the final block runs the finalize that
//   used to be a separate dispatch. Removes 2 dispatches + the final
//   kernel's serial-load latency from the ~179 µs constant residual.
__global__ __launch_bounds__(NTHR, 8) void bt_fused_kernel(
    const nf4* __restrict__ e4, const nf4* __restrict__ t4,
    float* __restrict__ acc, unsigned* __restrict__ cnt,
    float* __restrict__ out, int B, int nslot)
{
    const int tid = threadIdx.x;
    const int c4  = tid & (BT_D4 - 1);
    const int r   = tid >> 7;            // 0..3 (four 128-thread groups)

    float4 se  = make_float4(0.f, 0.f, 0.f, 0.f);
    float4 se2 = make_float4(0.f, 0.f, 0.f, 0.f);
    float4 st  = make_float4(0.f, 0.f, 0.f, 0.f);
    float4 st2 = make_float4(0.f, 0.f, 0.f, 0.f);
    float4 set = make_float4(0.f, 0.f, 0.f, 0.f);

    const unsigned T  = (unsigned)gridDim.x * NTHR;
    const unsigned N4 = (unsigned)B * BT_D4;
    unsigned i = (unsigned)blockIdx.x * NTHR + tid;

    for (; i + T < N4; i += 2u * T) {
        const nf4 e0 = __builtin_nontemporal_load(e4 + i);
        const nf4 t0 = __builtin_nontemporal_load(t4 + i);
        const nf4 e1 = __builtin_nontemporal_load(e4 + i + T);
        const nf4 t1 = __builtin_nontemporal_load(t4 + i + T);
        BT_ACC(e0, t0);
        BT_ACC(e1, t1);
    }
    for (; i < N4; i += T) {
        const nf4 ev = __builtin_nontemporal_load(e4 + i);
        const nf4 tv = __builtin_nontemporal_load(t4 + i);
        BT_ACC(ev, tv);
    }

    // ---- Phase 2: LDS tree fold r{2,3}->r{0,1}, then r1->r0 -------------
    __shared__ float4  L[3][BT_D4][5];   // 30 KB, reused by phase 3
    __shared__ double  R[BT_D4];
    __shared__ unsigned lastblk;

    if (r >= 2) {
        float4 (*Lp)[5] = L[r - 2];
        Lp[c4][0] = se;  Lp[c4][1] = se2; Lp[c4][2] = st;
        Lp[c4][3] = st2; Lp[c4][4] = set;
    }
    __syncthreads();
    if (r < 2) {
        float4 (*Lp)[5] = L[r];
        BT_ADD4(se,  Lp[c4][0]); BT_ADD4(se2, Lp[c4][1]); BT_ADD4(st, Lp[c4][2]);
        BT_ADD4(st2, Lp[c4][3]); BT_ADD4(set, Lp[c4][4]);
    }
    __syncthreads();
    if (r == 1) {
        L[0][c4][0] = se;  L[0][c4][1] = se2; L[0][c4][2] = st;
        L[0][c4][3] = st2; L[0][c4][4] = set;
    }
    __syncthreads();
    if (r == 0) {
        BT_ADD4(se,  L[0][c4][0]); BT_ADD4(se2, L[0][c4][1]);
        BT_ADD4(st,  L[0][c4][2]); BT_ADD4(st2, L[0][c4][3]);
        BT_ADD4(set, L[0][c4][4]);

        float* ap = acc + (size_t)(blockIdx.x & (nslot - 1)) * (5 * BT_D);
        const int col = c4 * 4;
        atomicAdd(&ap[0 * BT_D + col + 0], se.x);
        atomicAdd(&ap[0 * BT_D + col + 1], se.y);
        atomicAdd(&ap[0 * BT_D + col + 2], se.z);
        atomicAdd(&ap[0 * BT_D + col + 3], se.w);
        atomicAdd(&ap[1 * BT_D + col + 0], se2.x);
        atomicAdd(&ap[1 * BT_D + col + 1], se2.y);
        atomicAdd(&ap[1 * BT_D + col + 2], se2.z);
        atomicAdd(&ap[1 * BT_D + col + 3], se2.w);
        atomicAdd(&ap[2 * BT_D + col + 0], st.x);
        atomicAdd(&ap[2 * BT_D + col + 1], st.y);
        atomicAdd(&ap[2 * BT_D + col + 2], st.z);
        atomicAdd(&ap[2 * BT_D + col + 3], st.w);
        atomicAdd(&ap[3 * BT_D + col + 0], st2.x);
        atomicAdd(&ap[3 * BT_D + col + 1], st2.y);
        atomicAdd(&ap[3 * BT_D + col + 2], st2.z);
        atomicAdd(&ap[3 * BT_D + col + 3], st2.w);
        atomicAdd(&ap[4 * BT_D + col + 0], set.x);
        atomicAdd(&ap[4 * BT_D + col + 1], set.y);
        atomicAdd(&ap[4 * BT_D + col + 2], set.z);
        atomicAdd(&ap[4 * BT_D + col + 3], set.w);
    }

    // ---- Phase 3: last block finalizes ----------------------------------
    // __syncthreads() drains vmcnt (all this block's atomics retired at the
    // device-coherent point); __threadfence() orders them vs the counter.
    __threadfence();
    __syncthreads();
    if (tid == 0)
        lastblk = (atomicAdd(cnt, 1u) == (unsigned)(NBLK - 1)) ? 1u : 0u;
    __syncthreads();
    if (!lastblk) return;
    __threadfence();   // acquire side
    asm volatile("" ::: "memory");

    // acc lines were only ever touched by device-scope atomics (coherent
    // point) — no stale L1/L2 copies exist, plain loads are safe.
    const int q = tid >> 7;   // slot phase 0..3
    float4 S0 = make_float4(0.f, 0.f, 0.f, 0.f);
    float4 S1 = S0, S2 = S0, S3 = S0, S4 = S0;
    const float4* a4 = (const float4*)acc;
    for (int s = q; s < nslot; s += 4) {
        const float4* a = a4 + (size_t)s * (5 * BT_D4);
        float4 x;
        x = a[0 * BT_D4 + c4]; BT_ADD4(S0, x);
        x = a[1 * BT_D4 + c4]; BT_ADD4(S1, x);
        x = a[2 * BT_D4 + c4]; BT_ADD4(S2, x);
        x = a[3 * BT_D4 + c4]; BT_ADD4(S3, x);
        x = a[4 * BT_D4 + c4]; BT_ADD4(S4, x);
    }
    if (q) {
        L[q - 1][c4][0] = S0; L[q - 1][c4][1] = S1; L[q - 1][c4][2] = S2;
        L[q - 1][c4][3] = S3; L[q - 1][c4][4] = S4;
    }
    __syncthreads();
    if (q == 0) {
        for (int j = 0; j < 3; ++j) {
            BT_ADD4(S0, L[j][c4][0]); BT_ADD4(S1, L[j][c4][1]);
            BT_ADD4(S2, L[j][c4][2]); BT_ADD4(S3, L[j][c4][3]);
            BT_ADD4(S4, L[j][c4][4]);
        }
        const double Bd = (double)B;
        double vsum = 0.0;
        BT_FIN(S0.x, S1.x, S2.x, S3.x, S4.x);
        BT_FIN(S0.y, S1.y, S2.y, S3.y, S4.y);
        BT_FIN(S0.z, S1.z, S2.z, S3.z, S4.z);
        BT_FIN(S0.w, S1.w, S2.w, S3.w, S4.w);
        R[c4] = vsum;
    }
    __syncthreads();
    for (int s2 = 64; s2 > 0; s2 >>= 1) {
        if (tid < s2) R[tid] += R[tid + s2];
        __syncthreads();
    }
    if (tid == 0) out[0] = (float)R[0];
}

extern "C" void kernel_launch(void* const* d_in, const int* in_sizes, int n_in,
                              void* d_out, int out_size, void* d_ws, size_t ws_size,
                              hipStream_t stream) {
    const float* e   = (const float*)d_in[0];
    const float* tau = (const float*)d_in[1];
    const int B = in_sizes[0] / BT_D;
    float* acc = (float*)d_ws;

    // accumulator copies: atomic same-address chain depth = NBLK / nslot;
    // +16 bytes for the completion counter.
    int nslot = 1;
    const size_t slot_bytes = (size_t)5 * BT_D * sizeof(float);
    if (ws_size >= 32 * slot_bytes + 16)      nslot = 32;
    else if (ws_size >= 8 * slot_bytes + 16)  nslot = 8;
    else if (ws_size >= 4 * slot_bytes + 16)  nslot = 4;
    else if (ws_size >= 2 * slot_bytes + 16)  nslot = 2;

    unsigned* cnt = (unsigned*)((char*)d_ws + (size_t)nslot * slot_bytes);

    (void)hipMemsetAsync(d_ws, 0, (size_t)nslot * slot_bytes + 16, stream);

    bt_fused_kernel<<<NBLK, NTHR, 0, stream>>>(
        (const nf4*)e, (const nf4*)tau, acc, cnt,
        (float*)d_out, B, nslot);
}

// Round 7
// 481.763 us; speedup vs baseline: 1.1747x; 1.1747x over previous
//
#include <hip/hip_runtime.h>

#define BT_D   512
#define BT_D4  128   // float4 groups per row
#define NBLK   1024  // grid is launched with exactly NBLK blocks
#define NTHR   256   // 4 waves/block; (256,4) -> 128-VGPR budget

typedef float nf4 __attribute__((ext_vector_type(4)));

// One pipeline stage: 8 PLAIN loads (4 e-chunks grouped, then 4 t-chunks).
// No inline asm: the sched_barrier(0) after the group pins the schedule
// (nothing may cross), and the compiler's waitcnt pass inserts the counted
// vmcnt itself — provably matched to the loads it covers.
#define BT_LOAD8(P, base_) do {                                           \
        const unsigned _b = (base_);                                      \
        P##e0 = e4[_b];          P##e1 = e4[_b + T];                      \
        P##e2 = e4[_b + 2 * T];  P##e3 = e4[_b + 3 * T];                  \
        P##t0 = t4[_b];          P##t1 = t4[_b + T];                      \
        P##t2 = t4[_b + 2 * T];  P##t3 = t4[_b + 3 * T];                  \
    } while (0)

#define BT_ACC(ev, tv)                                                  \
    do {                                                                \
        se.x += (ev).x; se.y += (ev).y; se.z += (ev).z; se.w += (ev).w; \
        st.x += (tv).x; st.y += (tv).y; st.z += (tv).z; st.w += (tv).w; \
        se2.x = fmaf((ev).x, (ev).x, se2.x);                            \
        se2.y = fmaf((ev).y, (ev).y, se2.y);                            \
        se2.z = fmaf((ev).z, (ev).z, se2.z);                            \
        se2.w = fmaf((ev).w, (ev).w, se2.w);                            \
        st2.x = fmaf((tv).x, (tv).x, st2.x);                            \
        st2.y = fmaf((tv).y, (tv).y, st2.y);                            \
        st2.z = fmaf((tv).z, (tv).z, st2.z);                            \
        st2.w = fmaf((tv).w, (tv).w, st2.w);                            \
        set.x = fmaf((ev).x, (tv).x, set.x);                            \
        set.y = fmaf((ev).y, (tv).y, set.y);                            \
        set.z = fmaf((ev).z, (tv).z, set.z);                            \
        set.w = fmaf((ev).w, (tv).w, set.w);                            \
    } while (0)

#define BT_CONSUME(P) do { BT_ACC(P##e0, P##t0); BT_ACC(P##e1, P##t1); \
                           BT_ACC(P##e2, P##t2); BT_ACC(P##e3, P##t3); } while (0)

#define BT_ADD4(dst, a) \
    do { (dst).x += (a).x; (dst).y += (a).y; (dst).z += (a).z; (dst).w += (a).w; } while (0)

#define BT_FIN(Se_, Se2_, St_, St2_, Set_)                               \
    do {                                                                 \
        const double Se = (Se_), Se2 = (Se2_), St = (St_), St2 = (St2_), \
                     Set = (Set_);                                       \
        const double me = Se / Bd, mt = St / Bd;                         \
        double ve = (Se2 - Bd * me * me) / (Bd - 1.0);                   \
        double vt = (St2 - Bd * mt * mt) / (Bd - 1.0);                   \
        ve = ve > 0.0 ? ve : 0.0;                                        \
        vt = vt > 0.0 ? vt : 0.0;                                        \
        const double sd_e = sqrt(ve) + 1e-9;                             \
        const double sd_t = sqrt(vt) + 1e-9;                             \
        const double c = (Set - Bd * me * mt) / (sd_e * sd_t * Bd);      \
        vsum += (1.0 - c) * (1.0 - c);                                   \
    } while (0)

__global__ __launch_bounds__(NTHR, 4) void bt_fused_kernel(
    const nf4* __restrict__ e4, const nf4* __restrict__ t4,
    float* __restrict__ acc, unsigned* __restrict__ cnt,
    float* __restrict__ out, int B, int nslot)
{
    const int tid = threadIdx.x;
    const int c4  = tid & (BT_D4 - 1);
    const int r   = tid >> 7;            // 0..1

    float4 se  = make_float4(0.f, 0.f, 0.f, 0.f);
    float4 se2 = make_float4(0.f, 0.f, 0.f, 0.f);
    float4 st  = make_float4(0.f, 0.f, 0.f, 0.f);
    float4 st2 = make_float4(0.f, 0.f, 0.f, 0.f);
    float4 set = make_float4(0.f, 0.f, 0.f, 0.f);

    constexpr unsigned T = (unsigned)NBLK * NTHR;     // compile-time stride
    const unsigned N4 = (unsigned)B * BT_D4;
    const unsigned i0 = (unsigned)blockIdx.x * NTHR + tid;

    // per-thread chunk count; stages of 4 chunks, depth-2 pipelined
    unsigned rem = (i0 < N4) ? ((N4 - 1 - i0) / T + 1) : 0;
    const unsigned nst = rem >> 2;
    const unsigned tl  = rem & 3;

    nf4 Ae0, Ae1, Ae2, Ae3, At0, At1, At2, At3;
    nf4 Be0, Be1, Be2, Be3, Bt0, Bt1, Bt2, Bt3;

    unsigned ip = i0;
    if (nst) { BT_LOAD8(A, ip); ip += 4u * T; }
    for (unsigned s = 1; s < nst; ++s) {
        if (s & 1u) {
            BT_LOAD8(B, ip);                      // 8 loads in flight on top of A's
            __builtin_amdgcn_sched_barrier(0);    // loads may not sink past here
            BT_CONSUME(A);                        // compiler emits vmcnt(8) wait
        } else {
            BT_LOAD8(A, ip);
            __builtin_amdgcn_sched_barrier(0);
            BT_CONSUME(B);
        }
        ip += 4u * T;
    }
    if (nst) {
        if (nst & 1u) BT_CONSUME(A);
        else          BT_CONSUME(B);
    }
    // tail chunks (0 iterations for B=65536)
    unsigned it = i0 + (nst << 2) * T;
    for (unsigned j = 0; j < tl; ++j, it += T) {
        const nf4 ev = e4[it];
        const nf4 tv = t4[it];
        BT_ACC(ev, tv);
    }

    // ---- block fold: r1 -> r0 ------------------------------------------
    __shared__ float4  L[BT_D4][5];      // 10 KB, reused by finalize
    __shared__ double  R[BT_D4];
    __shared__ unsigned lastblk;

    if (r == 1) {
        L[c4][0] = se;  L[c4][1] = se2; L[c4][2] = st;
        L[c4][3] = st2; L[c4][4] = set;
    }
    __syncthreads();
    if (r == 0) {
        BT_ADD4(se,  L[c4][0]); BT_ADD4(se2, L[c4][1]); BT_ADD4(st, L[c4][2]);
        BT_ADD4(st2, L[c4][3]); BT_ADD4(set, L[c4][4]);

        float* ap = acc + (size_t)(blockIdx.x & (nslot - 1)) * (5 * BT_D);
        const int col = c4 * 4;
        atomicAdd(&ap[0 * BT_D + col + 0], se.x);
        atomicAdd(&ap[0 * BT_D + col + 1], se.y);
        atomicAdd(&ap[0 * BT_D + col + 2], se.z);
        atomicAdd(&ap[0 * BT_D + col + 3], se.w);
        atomicAdd(&ap[1 * BT_D + col + 0], se2.x);
        atomicAdd(&ap[1 * BT_D + col + 1], se2.y);
        atomicAdd(&ap[1 * BT_D + col + 2], se2.z);
        atomicAdd(&ap[1 * BT_D + col + 3], se2.w);
        atomicAdd(&ap[2 * BT_D + col + 0], st.x);
        atomicAdd(&ap[2 * BT_D + col + 1], st.y);
        atomicAdd(&ap[2 * BT_D + col + 2], st.z);
        atomicAdd(&ap[2 * BT_D + col + 3], st.w);
        atomicAdd(&ap[3 * BT_D + col + 0], st2.x);
        atomicAdd(&ap[3 * BT_D + col + 1], st2.y);
        atomicAdd(&ap[3 * BT_D + col + 2], st2.z);
        atomicAdd(&ap[3 * BT_D + col + 3], st2.w);
        atomicAdd(&ap[4 * BT_D + col + 0], set.x);
        atomicAdd(&ap[4 * BT_D + col + 1], set.y);
        atomicAdd(&ap[4 * BT_D + col + 2], set.z);
        atomicAdd(&ap[4 * BT_D + col + 3], set.w);
    }

    // ---- last block finalizes (R4-validated fence structure) ------------
    __threadfence();
    __syncthreads();
    if (tid == 0)
        lastblk = (atomicAdd(cnt, 1u) == (unsigned)(NBLK - 1)) ? 1u : 0u;
    __syncthreads();
    if (!lastblk) return;
    __threadfence();
    asm volatile("" ::: "memory");

    const int q = tid >> 7;   // 0..1
    float4 S0 = make_float4(0.f, 0.f, 0.f, 0.f);
    float4 S1 = S0, S2 = S0, S3 = S0, S4 = S0;
    const float4* a4 = (const float4*)acc;
    for (int s = q; s < nslot; s += 2) {
        const float4* a = a4 + (size_t)s * (5 * BT_D4);
        float4 x;
        x = a[0 * BT_D4 + c4]; BT_ADD4(S0, x);
        x = a[1 * BT_D4 + c4]; BT_ADD4(S1, x);
        x = a[2 * BT_D4 + c4]; BT_ADD4(S2, x);
        x = a[3 * BT_D4 + c4]; BT_ADD4(S3, x);
        x = a[4 * BT_D4 + c4]; BT_ADD4(S4, x);
    }
    if (q == 1) {
        L[c4][0] = S0; L[c4][1] = S1; L[c4][2] = S2;
        L[c4][3] = S3; L[c4][4] = S4;
    }
    __syncthreads();
    if (q == 0) {
        BT_ADD4(S0, L[c4][0]); BT_ADD4(S1, L[c4][1]); BT_ADD4(S2, L[c4][2]);
        BT_ADD4(S3, L[c4][3]); BT_ADD4(S4, L[c4][4]);
        const double Bd = (double)B;
        double vsum = 0.0;
        BT_FIN(S0.x, S1.x, S2.x, S3.x, S4.x);
        BT_FIN(S0.y, S1.y, S2.y, S3.y, S4.y);
        BT_FIN(S0.z, S1.z, S2.z, S3.z, S4.z);
        BT_FIN(S0.w, S1.w, S2.w, S3.w, S4.w);
        R[c4] = vsum;
    }
    __syncthreads();
    for (int s2 = 64; s2 > 0; s2 >>= 1) {
        if (tid < s2) R[tid] += R[tid + s2];
        __syncthreads();
    }
    if (tid == 0) out[0] = (float)R[0];
}

extern "C" void kernel_launch(void* const* d_in, const int* in_sizes, int n_in,
                              void* d_out, int out_size, void* d_ws, size_t ws_size,
                              hipStream_t stream) {
    const float* e   = (const float*)d_in[0];
    const float* tau = (const float*)d_in[1];
    const int B = in_sizes[0] / BT_D;
    float* acc = (float*)d_ws;

    int nslot = 1;
    const size_t slot_bytes = (size_t)5 * BT_D * sizeof(float);
    if (ws_size >= 32 * slot_bytes + 16)      nslot = 32;
    else if (ws_size >= 8 * slot_bytes + 16)  nslot = 8;
    else if (ws_size >= 4 * slot_bytes + 16)  nslot = 4;
    else if (ws_size >= 2 * slot_bytes + 16)  nslot = 2;

    unsigned* cnt = (unsigned*)((char*)d_ws + (size_t)nslot * slot_bytes);

    (void)hipMemsetAsync(d_ws, 0, (size_t)nslot * slot_bytes + 16, stream);

    bt_fused_kernel<<<NBLK, NTHR, 0, stream>>>(
        (const nf4*)e, (const nf4*)tau, acc, cnt,
        (float*)d_out, B, nslot);
}

// Round 8
// 369.584 us; speedup vs baseline: 1.5313x; 1.3035x over previous
//
#include <hip/hip_runtime.h>

#define BT_D   512
#define BT_D4  128   // float4 groups per row
#define NBLK   1024
#define NTHR   256   // 4 waves: waves 0-1 load e, waves 2-3 load t
#define CHK    256   // float4 per chunk per array (4 KB each)

typedef float nf4 __attribute__((ext_vector_type(4)));

#define BT_ACC(ev, tv)                                                  \
    do {                                                                \
        se.x += (ev).x; se.y += (ev).y; se.z += (ev).z; se.w += (ev).w; \
        st.x += (tv).x; st.y += (tv).y; st.z += (tv).z; st.w += (tv).w; \
        se2.x = fmaf((ev).x, (ev).x, se2.x);                            \
        se2.y = fmaf((ev).y, (ev).y, se2.y);                            \
        se2.z = fmaf((ev).z, (ev).z, se2.z);                            \
        se2.w = fmaf((ev).w, (ev).w, se2.w);                            \
        st2.x = fmaf((tv).x, (tv).x, st2.x);                            \
        st2.y = fmaf((tv).y, (tv).y, st2.y);                            \
        st2.z = fmaf((tv).z, (tv).z, st2.z);                            \
        st2.w = fmaf((tv).w, (tv).w, st2.w);                            \
        set.x = fmaf((ev).x, (tv).x, set.x);                            \
        set.y = fmaf((ev).y, (tv).y, set.y);                            \
        set.z = fmaf((ev).z, (tv).z, set.z);                            \
        set.w = fmaf((ev).w, (tv).w, set.w);                            \
    } while (0)

#define BT_ADD4(dst, a) \
    do { (dst).x += (a).x; (dst).y += (a).y; (dst).z += (a).z; (dst).w += (a).w; } while (0)

#define BT_FIN(Se_, Se2_, St_, St2_, Set_)                               \
    do {                                                                 \
        const double Se = (Se_), Se2 = (Se2_), St = (St_), St2 = (St2_), \
                     Set = (Set_);                                       \
        const double me = Se / Bd, mt = St / Bd;                         \
        double ve = (Se2 - Bd * me * me) / (Bd - 1.0);                   \
        double vt = (St2 - Bd * mt * mt) / (Bd - 1.0);                   \
        ve = ve > 0.0 ? ve : 0.0;                                        \
        vt = vt > 0.0 ? vt : 0.0;                                        \
        const double sd_e = sqrt(ve) + 1e-9;                             \
        const double sd_t = sqrt(vt) + 1e-9;                             \
        const double c = (Set - Bd * me * mt) / (sd_e * sd_t * Bd);      \
        vsum += (1.0 - c) * (1.0 - c);                                   \
    } while (0)

// Wave-specialized streaming: every wave issues loads for exactly ONE array
// (waves 0-1: e, waves 2-3: t); pairing happens via an LDS double-buffer.
// Tests (and if real, fixes) the per-wave dual-stream alternation wall: all
// prior structures (107-131 µs) had each wave alternating between addresses
// 2^27 bytes apart; this is the one untested variable. Global order keeps
// R1's dense moving-front: chunk c = s*NBLK + bid.
__global__ __launch_bounds__(NTHR, 4) void bt_fused_kernel(
    const nf4* __restrict__ e4, const nf4* __restrict__ t4,
    float* __restrict__ acc, unsigned* __restrict__ cnt,
    float* __restrict__ out, int B, int nslot)
{
    const int tid  = threadIdx.x;
    const int c4   = tid & (BT_D4 - 1);
    const int half = tid >> 7;           // 0: e-loader, 1: t-loader
    const int lt   = tid & 127;          // loader lane within half

    __shared__ nf4    SE[2][CHK];        // 8 KB
    __shared__ nf4    ST[2][CHK];        // 8 KB
    __shared__ float4 L[BT_D4][5];       // 10 KB (fold + finalize scratch)
    __shared__ double R[BT_D4];
    __shared__ unsigned lastblk;

    float4 se  = make_float4(0.f, 0.f, 0.f, 0.f);
    float4 se2 = make_float4(0.f, 0.f, 0.f, 0.f);
    float4 st  = make_float4(0.f, 0.f, 0.f, 0.f);
    float4 st2 = make_float4(0.f, 0.f, 0.f, 0.f);
    float4 set = make_float4(0.f, 0.f, 0.f, 0.f);

    const unsigned N4 = (unsigned)B * BT_D4;
    const unsigned C  = N4 / CHK;        // full chunks over both arrays
    const nf4* __restrict__ src = half ? t4 : e4;

    unsigned c = blockIdx.x;
    bool have = (c < C);
    nf4 ra, rb;
    if (have) {
        const unsigned b4 = c * CHK;
        ra = src[b4 + lt];
        rb = src[b4 + lt + 128];
    }
    int cur = 0;
    while (have) {
        // stage my array's half-chunk into LDS[cur]
        if (!half) { SE[cur][lt] = ra; SE[cur][lt + 128] = rb; }
        else       { ST[cur][lt] = ra; ST[cur][lt + 128] = rb; }
        // issue next chunk's loads (in flight across barrier + consume)
        const unsigned cn = c + NBLK;
        const bool havn = (cn < C);
        if (havn) {
            const unsigned b4 = cn * CHK;
            ra = src[b4 + lt];
            rb = src[b4 + lt + 128];
        }
        __syncthreads();
        // consume position tid: global idx = c*CHK + tid, column = tid&127.
        // Single barrier/iter is safe: next write targets LDS[cur^1], last
        // consumed one full iteration (and one barrier) ago.
        {
            const nf4 ev = SE[cur][tid];
            const nf4 tv = ST[cur][tid];
            BT_ACC(ev, tv);
        }
        c = cn; have = havn; cur ^= 1;
    }
    // tail (N4 % CHK != 0; empty for B=65536). idx&127 == tid&127 holds.
    for (unsigned i = C * CHK + tid; i < N4; i += NTHR) {
        const nf4 ev = e4[i];
        const nf4 tv = t4[i];
        BT_ACC(ev, tv);
    }

    // ---- block fold: half1 -> half0 -------------------------------------
    __syncthreads();    // all consumes done before L reuse
    if (half == 1) {
        L[c4][0] = se;  L[c4][1] = se2; L[c4][2] = st;
        L[c4][3] = st2; L[c4][4] = set;
    }
    __syncthreads();
    if (half == 0) {
        BT_ADD4(se,  L[c4][0]); BT_ADD4(se2, L[c4][1]); BT_ADD4(st, L[c4][2]);
        BT_ADD4(st2, L[c4][3]); BT_ADD4(set, L[c4][4]);

        float* ap = acc + (size_t)(blockIdx.x & (nslot - 1)) * (5 * BT_D);
        const int col = c4 * 4;
        atomicAdd(&ap[0 * BT_D + col + 0], se.x);
        atomicAdd(&ap[0 * BT_D + col + 1], se.y);
        atomicAdd(&ap[0 * BT_D + col + 2], se.z);
        atomicAdd(&ap[0 * BT_D + col + 3], se.w);
        atomicAdd(&ap[1 * BT_D + col + 0], se2.x);
        atomicAdd(&ap[1 * BT_D + col + 1], se2.y);
        atomicAdd(&ap[1 * BT_D + col + 2], se2.z);
        atomicAdd(&ap[1 * BT_D + col + 3], se2.w);
        atomicAdd(&ap[2 * BT_D + col + 0], st.x);
        atomicAdd(&ap[2 * BT_D + col + 1], st.y);
        atomicAdd(&ap[2 * BT_D + col + 2], st.z);
        atomicAdd(&ap[2 * BT_D + col + 3], st.w);
        atomicAdd(&ap[3 * BT_D + col + 0], st2.x);
        atomicAdd(&ap[3 * BT_D + col + 1], st2.y);
        atomicAdd(&ap[3 * BT_D + col + 2], st2.z);
        atomicAdd(&ap[3 * BT_D + col + 3], st2.w);
        atomicAdd(&ap[4 * BT_D + col + 0], set.x);
        atomicAdd(&ap[4 * BT_D + col + 1], set.y);
        atomicAdd(&ap[4 * BT_D + col + 2], set.z);
        atomicAdd(&ap[4 * BT_D + col + 3], set.w);
    }

    // ---- last block finalizes (R4-validated fence structure) ------------
    __threadfence();
    __syncthreads();
    if (tid == 0)
        lastblk = (atomicAdd(cnt, 1u) == (unsigned)(NBLK - 1)) ? 1u : 0u;
    __syncthreads();
    if (!lastblk) return;
    __threadfence();
    asm volatile("" ::: "memory");

    const int q = half;   // 0..1
    float4 S0 = make_float4(0.f, 0.f, 0.f, 0.f);
    float4 S1 = S0, S2 = S0, S3 = S0, S4 = S0;
    const float4* a4 = (const float4*)acc;
    for (int s = q; s < nslot; s += 2) {
        const float4* a = a4 + (size_t)s * (5 * BT_D4);
        float4 x;
        x = a[0 * BT_D4 + c4]; BT_ADD4(S0, x);
        x = a[1 * BT_D4 + c4]; BT_ADD4(S1, x);
        x = a[2 * BT_D4 + c4]; BT_ADD4(S2, x);
        x = a[3 * BT_D4 + c4]; BT_ADD4(S3, x);
        x = a[4 * BT_D4 + c4]; BT_ADD4(S4, x);
    }
    if (q == 1) {
        L[c4][0] = S0; L[c4][1] = S1; L[c4][2] = S2;
        L[c4][3] = S3; L[c4][4] = S4;
    }
    __syncthreads();
    if (q == 0) {
        BT_ADD4(S0, L[c4][0]); BT_ADD4(S1, L[c4][1]); BT_ADD4(S2, L[c4][2]);
        BT_ADD4(S3, L[c4][3]); BT_ADD4(S4, L[c4][4]);
        const double Bd = (double)B;
        double vsum = 0.0;
        BT_FIN(S0.x, S1.x, S2.x, S3.x, S4.x);
        BT_FIN(S0.y, S1.y, S2.y, S3.y, S4.y);
        BT_FIN(S0.z, S1.z, S2.z, S3.z, S4.z);
        BT_FIN(S0.w, S1.w, S2.w, S3.w, S4.w);
        R[c4] = vsum;
    }
    __syncthreads();
    for (int s2 = 64; s2 > 0; s2 >>= 1) {
        if (tid < s2) R[tid] += R[tid + s2];
        __syncthreads();
    }
    if (tid == 0) out[0] = (float)R[0];
}

extern "C" void kernel_launch(void* const* d_in, const int* in_sizes, int n_in,
                              void* d_out, int out_size, void* d_ws, size_t ws_size,
                              hipStream_t stream) {
    const float* e   = (const float*)d_in[0];
    const float* tau = (const float*)d_in[1];
    const int B = in_sizes[0] / BT_D;
    float* acc = (float*)d_ws;

    int nslot = 1;
    const size_t slot_bytes = (size_t)5 * BT_D * sizeof(float);
    if (ws_size >= 32 * slot_bytes + 16)      nslot = 32;
    else if (ws_size >= 8 * slot_bytes + 16)  nslot = 8;
    else if (ws_size >= 4 * slot_bytes + 16)  nslot = 4;
    else if (ws_size >= 2 * slot_bytes + 16)  nslot = 2;

    unsigned* cnt = (unsigned*)((char*)d_ws + (size_t)nslot * slot_bytes);

    (void)hipMemsetAsync(d_ws, 0, (size_t)nslot * slot_bytes + 16, stream);

    bt_fused_kernel<<<NBLK, NTHR, 0, stream>>>(
        (const nf4*)e, (const nf4*)tau, acc, cnt,
        (float*)d_out, B, nslot);
}